// Round 11
// baseline (52.055 us; speedup 1.0000x reference)
//
#include <hip/hip_runtime.h>

#define BB 8192
#define SEQF 2560      // floats per sequence (512*5)

typedef float v2f __attribute__((ext_vector_type(2)));
typedef float v4f __attribute__((ext_vector_type(4)));   // native vec for nontemporal builtins

__device__ __forceinline__ float rfl(float x) {
    return __int_as_float(__builtin_amdgcn_readfirstlane(__float_as_int(x)));
}
__device__ __forceinline__ v2f vsplat(float x) { return (v2f){x, x}; }

// R7 structure exactly, with NONTEMPORAL loads (read-once stream, no cache
// allocation). Wave = 2 sequences: lanes 0-31 scan seq A, lanes 32-63 seq B.
// Lane: 16 timesteps (320B contiguous). Packed-f32 3x3 transfer matrices,
// shared 5-level suffix tree, exact power-of-two renorm, e^-2 bias folded
// into E/C (compensated exactly at the end).
__global__ __launch_bounds__(128, 4) void crf_fused(const float* __restrict__ feats,
                                                    const float* __restrict__ trans,
                                                    float* __restrict__ out) {
    const int tid  = threadIdx.x;
    const int lane = tid & 63;
    const int half = lane >> 5;      // which sequence of the pair
    const int cpos = lane & 31;      // chunk index within the sequence
    const int wv   = tid >> 6;
    const int s0   = (blockIdx.x * 2 + wv) * 2;

    // ---- issue ALL 20 loads up front (contiguous 320 B per lane), NT ----
    const v4f* p = (const v4f*)(feats + (size_t)(s0 + half) * SEQF) + cpos * 20;
    v4f q0 =__builtin_nontemporal_load(p+0),  q1 =__builtin_nontemporal_load(p+1);
    v4f q2 =__builtin_nontemporal_load(p+2),  q3 =__builtin_nontemporal_load(p+3);
    v4f q4 =__builtin_nontemporal_load(p+4),  q5 =__builtin_nontemporal_load(p+5);
    v4f q6 =__builtin_nontemporal_load(p+6),  q7 =__builtin_nontemporal_load(p+7);
    v4f q8 =__builtin_nontemporal_load(p+8),  q9 =__builtin_nontemporal_load(p+9);
    v4f q10=__builtin_nontemporal_load(p+10), q11=__builtin_nontemporal_load(p+11);
    v4f q12=__builtin_nontemporal_load(p+12), q13=__builtin_nontemporal_load(p+13);
    v4f q14=__builtin_nontemporal_load(p+14), q15=__builtin_nontemporal_load(p+15);
    v4f q16=__builtin_nontemporal_load(p+16), q17=__builtin_nontemporal_load(p+17);
    v4f q18=__builtin_nontemporal_load(p+18), q19=__builtin_nontemporal_load(p+19);
    __builtin_amdgcn_sched_barrier(0);   // pin loads first (max queue depth)

    // ---- uniform transition factors -> SGPRs; bias e^-2 folded in ----
    const float BIAS = 0.13533528323661270f;   // e^-2
    const float E00=rfl(__expf(trans[0])*BIAS),  E01=rfl(__expf(trans[1])*BIAS),  E02=rfl(__expf(trans[2])*BIAS);
    const float E10=rfl(__expf(trans[5])*BIAS),  E11=rfl(__expf(trans[6])*BIAS),  E12=rfl(__expf(trans[7])*BIAS);
    const float E20=rfl(__expf(trans[10])*BIAS), E21=rfl(__expf(trans[11])*BIAS), E22=rfl(__expf(trans[12])*BIAS);
    const float C0 =rfl(__expf(trans[3])*BIAS),  C1 =rfl(__expf(trans[8])*BIAS),  C2 =rfl(__expf(trans[13])*BIAS);
    const float S0 =rfl(__expf(trans[20])), S1 =rfl(__expf(trans[21])), S2 =rfl(__expf(trans[22]));

    const v2f E00p=vsplat(E00), E01p=vsplat(E01), E02p=vsplat(E02);
    const v2f E10p=vsplat(E10), E11p=vsplat(E11), E12p=vsplat(E12);
    const v2f E20p=vsplat(E20), E21p=vsplat(E21), E22p=vsplat(E22);

    // first-step factor: chunk 0 of each sequence starts from the START column
    const bool c0 = (cpos == 0);
    const v2f GA0 = c0 ? vsplat(C0) : (v2f){E00, E01};
    const v2f GA1 = c0 ? vsplat(C1) : (v2f){E10, E11};
    const v2f GA2 = c0 ? vsplat(C2) : (v2f){E20, E21};
    const float GB0 = c0 ? C0 : E02;
    const float GB1 = c0 ? C1 : E12;
    const float GB2 = c0 ? C2 : E22;

    // state: MA_i = (M_i0, M_i1) packed; MB_i = M_i2
    v2f MA0, MA1, MA2;
    float MB0, MB1, MB2;
    float ls = 0.0f;

#define CRF_STEP(FA, FB, FC) do {                                   \
        float e0 = __expf(FA), e1 = __expf(FB), e2 = __expf(FC);    \
        v2f NA0 = vsplat(e0) * (E00p*MA0 + E01p*MA1 + E02p*MA2);    \
        v2f NA1 = vsplat(e1) * (E10p*MA0 + E11p*MA1 + E12p*MA2);    \
        v2f NA2 = vsplat(e2) * (E20p*MA0 + E21p*MA1 + E22p*MA2);    \
        float NB0 = e0 * (E00*MB0 + E01*MB1 + E02*MB2);             \
        float NB1 = e1 * (E10*MB0 + E11*MB1 + E12*MB2);             \
        float NB2 = e2 * (E20*MB0 + E21*MB1 + E22*MB2);             \
        MA0=NA0; MA1=NA1; MA2=NA2; MB0=NB0; MB1=NB1; MB2=NB2;       \
    } while (0)

    // exact power-of-two renorm; ls counts the exponent (units of ln2)
#define CRF_RENORM() do {                                           \
        v2f mp = __builtin_elementwise_max(__builtin_elementwise_max(MA0, MA1), MA2); \
        float mm = fmaxf(fmaxf(mp.x, mp.y), fmaxf(fmaxf(MB0, MB1), MB2)); \
        mm = fmaxf(mm, 1e-30f);                                     \
        int ee = (int)((__float_as_uint(mm) >> 23) & 0xffu) - 127;  \
        float sc = __uint_as_float((unsigned)(127 - ee) << 23);     \
        ls += (float)ee;                                            \
        v2f scp = vsplat(sc);                                       \
        MA0*=scp; MA1*=scp; MA2*=scp; MB0*=sc; MB1*=sc; MB2*=sc;    \
    } while (0)

    // suffix-scan level: P = lane+D (later in time); M <- P * M
#define TREE_LEVEL(D, RN) do {                                      \
        v2f PA0, PA1, PA2;                                          \
        PA0.x=__shfl_down(MA0.x,D); PA0.y=__shfl_down(MA0.y,D);     \
        PA1.x=__shfl_down(MA1.x,D); PA1.y=__shfl_down(MA1.y,D);     \
        PA2.x=__shfl_down(MA2.x,D); PA2.y=__shfl_down(MA2.y,D);     \
        float PB0=__shfl_down(MB0,D), PB1=__shfl_down(MB1,D), PB2=__shfl_down(MB2,D); \
        float Pls=__shfl_down(ls, D);                               \
        v2f NA0 = vsplat(PA0.x)*MA0 + vsplat(PA0.y)*MA1 + vsplat(PB0)*MA2; \
        v2f NA1 = vsplat(PA1.x)*MA0 + vsplat(PA1.y)*MA1 + vsplat(PB1)*MA2; \
        v2f NA2 = vsplat(PA2.x)*MA0 + vsplat(PA2.y)*MA1 + vsplat(PB2)*MA2; \
        float NB0 = PA0.x*MB0 + PA0.y*MB1 + PB0*MB2;                \
        float NB1 = PA1.x*MB0 + PA1.y*MB1 + PB1*MB2;                \
        float NB2 = PA2.x*MB0 + PA2.y*MB1 + PB2*MB2;                \
        MA0=NA0; MA1=NA1; MA2=NA2; MB0=NB0; MB1=NB1; MB2=NB2;       \
        ls += Pls;                                                  \
        if (RN) CRF_RENORM();                                       \
    } while (0)

    {   // t0: M = D(e) * G
        float e0 = __expf(q0.x), e1 = __expf(q0.y), e2 = __expf(q0.z);
        MA0 = vsplat(e0) * GA0;  MB0 = e0 * GB0;
        MA1 = vsplat(e1) * GA1;  MB1 = e1 * GB1;
        MA2 = vsplat(e2) * GA2;  MB2 = e2 * GB2;
    }
    CRF_STEP(q1.y,  q1.z,  q1.w);    // t1
    CRF_STEP(q2.z,  q2.w,  q3.x);    // t2
    CRF_STEP(q3.w,  q4.x,  q4.y);    // t3
    CRF_STEP(q5.x,  q5.y,  q5.z);    // t4
    CRF_STEP(q6.y,  q6.z,  q6.w);    // t5
    CRF_STEP(q7.z,  q7.w,  q8.x);    // t6
    CRF_STEP(q8.w,  q9.x,  q9.y);    // t7
    CRF_STEP(q10.x, q10.y, q10.z);   // t8
    CRF_STEP(q11.y, q11.z, q11.w);   // t9
    CRF_STEP(q12.z, q12.w, q13.x);   // t10
    CRF_STEP(q13.w, q14.x, q14.y);   // t11
    CRF_STEP(q15.x, q15.y, q15.z);   // t12
    CRF_STEP(q16.y, q16.z, q16.w);   // t13
    CRF_STEP(q17.z, q17.w, q18.x);   // t14
    CRF_STEP(q18.w, q19.x, q19.y);   // t15
    CRF_RENORM();

    // shared tree: lanes 0-31 compose seq A, lanes 32-63 compose seq B.
    TREE_LEVEL(1, 0);
    TREE_LEVEL(2, 0);
    TREE_LEVEL(4, 1);
    TREE_LEVEL(8, 0);
    TREE_LEVEL(16, 1);

    // lanes 0 and 32: column 0 = full product applied to START-init vector.
    // Bias compensation: 512 biased factors * 2.0 = +1024 (exact).
    float r = S0*MA0.x + S1*MA1.x + S2*MA2.x;
    float res = __logf(r) + ls * 0.69314718055994531f + 1024.0f;
    if (cpos == 0) __builtin_nontemporal_store(res, &out[s0 + half]);

#undef CRF_STEP
#undef CRF_RENORM
#undef TREE_LEVEL
}

extern "C" void kernel_launch(void* const* d_in, const int* in_sizes, int n_in,
                              void* d_out, int out_size, void* d_ws, size_t ws_size,
                              hipStream_t stream) {
    const float* feats = (const float*)d_in[0];
    const float* trans = (const float*)d_in[1];
    float* out = (float*)d_out;
    (void)d_ws; (void)ws_size;

    crf_fused<<<BB / 4, 128, 0, stream>>>(feats, trans, out);
}

// Round 12
// 19.215 us; speedup vs baseline: 2.7091x; 2.7091x over previous
//
#include <hip/hip_runtime.h>

#define BB 8192
#define SEQF 2560      // floats per sequence (512*5)

typedef float v2f __attribute__((ext_vector_type(2)));

__device__ __forceinline__ float rfl(float x) {
    return __int_as_float(__builtin_amdgcn_readfirstlane(__float_as_int(x)));
}
__device__ __forceinline__ v2f vsplat(float x) { return (v2f){x, x}; }

// MAX-OCCUPANCY variant: one sequence per wave (8192 waves, 32 waves/CU at
// VGPR<=64). Lane owns 8 timesteps (40 floats = 10 float4, contiguous 160B).
// Packed-f32 3x3 transfer matrices, full-wave 6-level shfl_down suffix tree,
// exact power-of-two renorm, e^-2 bias folded into E/C (compensated +1024).
__global__ __launch_bounds__(256, 8) void crf_fused(const float* __restrict__ feats,
                                                    const float* __restrict__ trans,
                                                    float* __restrict__ out) {
    const int tid  = threadIdx.x;
    const int lane = tid & 63;
    const int wv   = tid >> 6;
    const int seq  = blockIdx.x * 4 + wv;

    // ---- issue ALL 10 loads up front (contiguous 160 B per lane) ----
    const float4* p = (const float4*)(feats + (size_t)seq * SEQF) + lane * 10;
    float4 q0=p[0], q1=p[1], q2=p[2], q3=p[3], q4=p[4];
    float4 q5=p[5], q6=p[6], q7=p[7], q8=p[8], q9=p[9];
    __builtin_amdgcn_sched_barrier(0);   // pin loads first (max queue depth)

    // ---- uniform transition factors -> SGPRs; bias e^-2 folded in ----
    const float BIAS = 0.13533528323661270f;   // e^-2
    const float E00=rfl(__expf(trans[0])*BIAS),  E01=rfl(__expf(trans[1])*BIAS),  E02=rfl(__expf(trans[2])*BIAS);
    const float E10=rfl(__expf(trans[5])*BIAS),  E11=rfl(__expf(trans[6])*BIAS),  E12=rfl(__expf(trans[7])*BIAS);
    const float E20=rfl(__expf(trans[10])*BIAS), E21=rfl(__expf(trans[11])*BIAS), E22=rfl(__expf(trans[12])*BIAS);
    const float C0 =rfl(__expf(trans[3])*BIAS),  C1 =rfl(__expf(trans[8])*BIAS),  C2 =rfl(__expf(trans[13])*BIAS);
    const float S0 =rfl(__expf(trans[20])), S1 =rfl(__expf(trans[21])), S2 =rfl(__expf(trans[22]));

    const v2f E00p=vsplat(E00), E01p=vsplat(E01), E02p=vsplat(E02);
    const v2f E10p=vsplat(E10), E11p=vsplat(E11), E12p=vsplat(E12);
    const v2f E20p=vsplat(E20), E21p=vsplat(E21), E22p=vsplat(E22);

    // first-step factor: lane 0 (chunk 0) starts from the START column
    const bool c0 = (lane == 0);
    const v2f GA0 = c0 ? vsplat(C0) : (v2f){E00, E01};
    const v2f GA1 = c0 ? vsplat(C1) : (v2f){E10, E11};
    const v2f GA2 = c0 ? vsplat(C2) : (v2f){E20, E21};
    const float GB0 = c0 ? C0 : E02;
    const float GB1 = c0 ? C1 : E12;
    const float GB2 = c0 ? C2 : E22;

    // state: MA_i = (M_i0, M_i1) packed; MB_i = M_i2
    v2f MA0, MA1, MA2;
    float MB0, MB1, MB2;
    float ls = 0.0f;

#define CRF_STEP(FA, FB, FC) do {                                   \
        float e0 = __expf(FA), e1 = __expf(FB), e2 = __expf(FC);    \
        v2f NA0 = vsplat(e0) * (E00p*MA0 + E01p*MA1 + E02p*MA2);    \
        v2f NA1 = vsplat(e1) * (E10p*MA0 + E11p*MA1 + E12p*MA2);    \
        v2f NA2 = vsplat(e2) * (E20p*MA0 + E21p*MA1 + E22p*MA2);    \
        float NB0 = e0 * (E00*MB0 + E01*MB1 + E02*MB2);             \
        float NB1 = e1 * (E10*MB0 + E11*MB1 + E12*MB2);             \
        float NB2 = e2 * (E20*MB0 + E21*MB1 + E22*MB2);             \
        MA0=NA0; MA1=NA1; MA2=NA2; MB0=NB0; MB1=NB1; MB2=NB2;       \
    } while (0)

    // exact power-of-two renorm; ls counts the exponent (units of ln2)
#define CRF_RENORM() do {                                           \
        v2f mp = __builtin_elementwise_max(__builtin_elementwise_max(MA0, MA1), MA2); \
        float mm = fmaxf(fmaxf(mp.x, mp.y), fmaxf(fmaxf(MB0, MB1), MB2)); \
        mm = fmaxf(mm, 1e-30f);                                     \
        int ee = (int)((__float_as_uint(mm) >> 23) & 0xffu) - 127;  \
        float sc = __uint_as_float((unsigned)(127 - ee) << 23);     \
        ls += (float)ee;                                            \
        v2f scp = vsplat(sc);                                       \
        MA0*=scp; MA1*=scp; MA2*=scp; MB0*=sc; MB1*=sc; MB2*=sc;    \
    } while (0)

    // suffix-scan level: P = lane+D (later in time); M <- P * M
#define TREE_LEVEL(D, RN) do {                                      \
        v2f PA0, PA1, PA2;                                          \
        PA0.x=__shfl_down(MA0.x,D); PA0.y=__shfl_down(MA0.y,D);     \
        PA1.x=__shfl_down(MA1.x,D); PA1.y=__shfl_down(MA1.y,D);     \
        PA2.x=__shfl_down(MA2.x,D); PA2.y=__shfl_down(MA2.y,D);     \
        float PB0=__shfl_down(MB0,D), PB1=__shfl_down(MB1,D), PB2=__shfl_down(MB2,D); \
        float Pls=__shfl_down(ls, D);                               \
        v2f NA0 = vsplat(PA0.x)*MA0 + vsplat(PA0.y)*MA1 + vsplat(PB0)*MA2; \
        v2f NA1 = vsplat(PA1.x)*MA0 + vsplat(PA1.y)*MA1 + vsplat(PB1)*MA2; \
        v2f NA2 = vsplat(PA2.x)*MA0 + vsplat(PA2.y)*MA1 + vsplat(PB2)*MA2; \
        float NB0 = PA0.x*MB0 + PA0.y*MB1 + PB0*MB2;                \
        float NB1 = PA1.x*MB0 + PA1.y*MB1 + PB1*MB2;                \
        float NB2 = PA2.x*MB0 + PA2.y*MB1 + PB2*MB2;                \
        MA0=NA0; MA1=NA1; MA2=NA2; MB0=NB0; MB1=NB1; MB2=NB2;       \
        ls += Pls;                                                  \
        if (RN) CRF_RENORM();                                       \
    } while (0)

    {   // t0: M = D(e) * G
        float e0 = __expf(q0.x), e1 = __expf(q0.y), e2 = __expf(q0.z);
        MA0 = vsplat(e0) * GA0;  MB0 = e0 * GB0;
        MA1 = vsplat(e1) * GA1;  MB1 = e1 * GB1;
        MA2 = vsplat(e2) * GA2;  MB2 = e2 * GB2;
    }
    CRF_STEP(q1.y, q1.z, q1.w);   // t1
    CRF_STEP(q2.z, q2.w, q3.x);   // t2
    CRF_STEP(q3.w, q4.x, q4.y);   // t3
    CRF_STEP(q5.x, q5.y, q5.z);   // t4
    CRF_STEP(q6.y, q6.z, q6.w);   // t5
    CRF_STEP(q7.z, q7.w, q8.x);   // t6
    CRF_STEP(q8.w, q9.x, q9.y);   // t7
    CRF_RENORM();

    // full-wave suffix tree over 64 chunks; renorm every 2 levels (bound 27)
    TREE_LEVEL(1, 0);
    TREE_LEVEL(2, 1);
    TREE_LEVEL(4, 0);
    TREE_LEVEL(8, 1);
    TREE_LEVEL(16, 0);
    TREE_LEVEL(32, 1);

    // lane 0: column 0 = full product applied to START-init vector.
    // Bias compensation: 512 biased factors * 2.0 = +1024 (exact).
    float r = S0*MA0.x + S1*MA1.x + S2*MA2.x;
    float res = __logf(r) + ls * 0.69314718055994531f + 1024.0f;
    if (lane == 0) out[seq] = res;

#undef CRF_STEP
#undef CRF_RENORM
#undef TREE_LEVEL
}

extern "C" void kernel_launch(void* const* d_in, const int* in_sizes, int n_in,
                              void* d_out, int out_size, void* d_ws, size_t ws_size,
                              hipStream_t stream) {
    const float* feats = (const float*)d_in[0];
    const float* trans = (const float*)d_in[1];
    float* out = (float*)d_out;
    (void)d_ws; (void)ws_size;

    crf_fused<<<BB / 4, 256, 0, stream>>>(feats, trans, out);
}